// Round 9
// baseline (199.804 us; speedup 1.0000x reference)
//
#include <hip/hip_runtime.h>

#define NN 50000
#define EE 600000
#define DD 128
#define LDSTR 136   // bf16 elems per LDS row: 272 B (16B-aligned, breaks pow2 bank stride)
#define MAXDEG 64   // degrees are Poisson(12); P(deg>64) ~ 1e-28
#define NSLICE 32   // privatized BN-stat copies
#define EPT 8       // edges per scatter thread

typedef __attribute__((ext_vector_type(8))) short short8;
typedef __attribute__((ext_vector_type(4))) float f32x4;

static __device__ __forceinline__ unsigned short f2bf(float f) {
    unsigned int u = __float_as_uint(f);
    u += 0x7FFF + ((u >> 16) & 1);   // round-to-nearest-even
    return (unsigned short)(u >> 16);
}
static __device__ __forceinline__ float bflo(unsigned int u) {
    return __uint_as_float(u << 16);
}
static __device__ __forceinline__ float bfhi(unsigned int u) {
    return __uint_as_float(u & 0xFFFF0000u);
}

// ---------------- prep + scatter fused ----------------

__global__ __launch_bounds__(256) void k_prep(const float* __restrict__ w1,
                                              const float* __restrict__ w2,
                                              const float* __restrict__ x,
                                              const int* __restrict__ ei,
                                              int* __restrict__ cursor,
                                              unsigned short* __restrict__ srcPad,
                                              unsigned short* __restrict__ wt,
                                              unsigned int* __restrict__ xb) {
    int tid = blockIdx.x * 256 + threadIdx.x;
    if (tid < EE / EPT) {
        #pragma unroll
        for (int i = 0; i < EPT; ++i) {
            int e = tid + i * (EE / EPT);
            int s = ei[e];
            int d = ei[EE + e];
            int pos = atomicAdd(&cursor[d], 1);
            if (pos < MAXDEG) srcPad[(d << 6) + pos] = (unsigned short)s;
        }
    }
    if (tid < 32768) {
        int w = tid >> 14, idx = tid & 16383;
        int k = idx >> 7, n = idx & 127;
        const float* src = w ? w2 : w1;
        wt[w * 16384 + n * 128 + k] = f2bf(src[k * 128 + n]);
    }
    int xi = tid - 32768;
    if (xi >= 0 && xi < NN * DD / 2) {
        float2 v = ((const float2*)x)[xi];
        xb[xi] = (unsigned int)f2bf(v.x) | ((unsigned int)f2bf(v.y) << 16);
    }
}

// ---------------- aggregation: h0 = bf16(x + sum_{src->i} x[src]) ----------------

__global__ __launch_bounds__(256) void k_agg(const unsigned int* __restrict__ xb,
                                             const int* __restrict__ cursor,
                                             const unsigned short* __restrict__ srcPad,
                                             unsigned int* __restrict__ h0) {
    int wave = (blockIdx.x * blockDim.x + threadIdx.x) >> 6;
    int lane = threadIdx.x & 63;
    if (wave >= NN) return;
    int cnt = cursor[wave];
    if (cnt > MAXDEG) cnt = MAXDEG;
    int sv = srcPad[(wave << 6) + lane];
    unsigned int self = xb[(wave << 6) + lane];
    float ax = bflo(self), ay = bfhi(self);
    int j = 0;
    for (; j + 8 <= cnt; j += 8) {
        int a0 = __shfl(sv, j, 64),     a1 = __shfl(sv, j + 1, 64);
        int a2 = __shfl(sv, j + 2, 64), a3 = __shfl(sv, j + 3, 64);
        int a4 = __shfl(sv, j + 4, 64), a5 = __shfl(sv, j + 5, 64);
        int a6 = __shfl(sv, j + 6, 64), a7 = __shfl(sv, j + 7, 64);
        unsigned int u0 = xb[(a0 << 6) + lane], u1 = xb[(a1 << 6) + lane];
        unsigned int u2 = xb[(a2 << 6) + lane], u3 = xb[(a3 << 6) + lane];
        unsigned int u4 = xb[(a4 << 6) + lane], u5 = xb[(a5 << 6) + lane];
        unsigned int u6 = xb[(a6 << 6) + lane], u7 = xb[(a7 << 6) + lane];
        ax += bflo(u0) + bflo(u1) + bflo(u2) + bflo(u3)
            + bflo(u4) + bflo(u5) + bflo(u6) + bflo(u7);
        ay += bfhi(u0) + bfhi(u1) + bfhi(u2) + bfhi(u3)
            + bfhi(u4) + bfhi(u5) + bfhi(u6) + bfhi(u7);
    }
    for (; j + 4 <= cnt; j += 4) {
        int a0 = __shfl(sv, j, 64),     a1 = __shfl(sv, j + 1, 64);
        int a2 = __shfl(sv, j + 2, 64), a3 = __shfl(sv, j + 3, 64);
        unsigned int u0 = xb[(a0 << 6) + lane], u1 = xb[(a1 << 6) + lane];
        unsigned int u2 = xb[(a2 << 6) + lane], u3 = xb[(a3 << 6) + lane];
        ax += bflo(u0) + bflo(u1) + bflo(u2) + bflo(u3);
        ay += bfhi(u0) + bfhi(u1) + bfhi(u2) + bfhi(u3);
    }
    for (; j < cnt; ++j) {
        int s = __shfl(sv, j, 64);
        unsigned int u = xb[(s << 6) + lane];
        ax += bflo(u);
        ay += bfhi(u);
    }
    h0[(wave << 6) + lane] = (unsigned int)f2bf(ax) | ((unsigned int)f2bf(ay) << 16);
}

// ---------------- fused 2-layer MLP: h2 = (relu(h0@W1+b1))@W2+b2, bf16 in/out ----------------
// No LDS for A/W (global->reg); h1 C-layout -> A-layout via LDS round-trip
// (each wave touches only its own 16 rows). h2 may alias h0 (rows read fully
// into regs before stores). Fused privatized BN pass-1 on output.

__global__ __launch_bounds__(256) void k_mlp(const unsigned short* A,
                                             const unsigned short* __restrict__ wt,
                                             const float* __restrict__ b1,
                                             const float* __restrict__ b2,
                                             unsigned short* C,
                                             float* __restrict__ priv) {
    __shared__ __align__(16) unsigned short H1s[64 * LDSTR];
    int t = threadIdx.x;
    int lane = t & 63, wid = t >> 6;
    int m = lane & 15, quad = lane >> 4;
    int row0 = blockIdx.x * 64 + wid * 16;   // this wave's 16 rows

    // A fragments (h0): 4 k-chunks, 16B/lane
    int gra = row0 + m;
    short8 af[4];
    #pragma unroll
    for (int kc = 0; kc < 4; ++kc)
        af[kc] = (gra < NN) ? *(const short8*)&A[gra * 128 + kc * 32 + quad * 8]
                            : (short8)0;

    // ---- GEMM1: acc = h0 @ W1 ----
    f32x4 acc[8];
    #pragma unroll
    for (int i = 0; i < 8; ++i) acc[i] = (f32x4)0.f;
    #pragma unroll
    for (int h = 0; h < 2; ++h) {
        short8 wf[4][4];
        #pragma unroll
        for (int nt = 0; nt < 4; ++nt)
            #pragma unroll
            for (int kc = 0; kc < 4; ++kc)
                wf[nt][kc] = *(const short8*)&wt[(h * 64 + nt * 16 + m) * 128 + kc * 32 + quad * 8];
        #pragma unroll
        for (int kc = 0; kc < 4; ++kc)
            #pragma unroll
            for (int nt = 0; nt < 4; ++nt)
                acc[h * 4 + nt] = __builtin_amdgcn_mfma_f32_16x16x32_bf16(af[kc], wf[nt][kc], acc[h * 4 + nt], 0, 0, 0);
    }

    // h1 = relu(acc + b1) -> LDS (C-layout scatter, wave-local rows)
    #pragma unroll
    for (int nt = 0; nt < 8; ++nt) {
        int col = nt * 16 + m;
        float bv = b1[col];
        #pragma unroll
        for (int r = 0; r < 4; ++r)
            H1s[(wid * 16 + quad * 4 + r) * LDSTR + col] = f2bf(fmaxf(acc[nt][r] + bv, 0.f));
    }
    __syncthreads();

    // A2 fragments from LDS (A-layout reads)
    short8 af2[4];
    #pragma unroll
    for (int kc = 0; kc < 4; ++kc)
        af2[kc] = *(const short8*)&H1s[(wid * 16 + m) * LDSTR + kc * 32 + quad * 8];

    // ---- GEMM2: acc = h1 @ W2 ----
    #pragma unroll
    for (int i = 0; i < 8; ++i) acc[i] = (f32x4)0.f;
    #pragma unroll
    for (int h = 0; h < 2; ++h) {
        short8 wf[4][4];
        #pragma unroll
        for (int nt = 0; nt < 4; ++nt)
            #pragma unroll
            for (int kc = 0; kc < 4; ++kc)
                wf[nt][kc] = *(const short8*)&wt[16384 + (h * 64 + nt * 16 + m) * 128 + kc * 32 + quad * 8];
        #pragma unroll
        for (int kc = 0; kc < 4; ++kc)
            #pragma unroll
            for (int nt = 0; nt < 4; ++nt)
                acc[h * 4 + nt] = __builtin_amdgcn_mfma_f32_16x16x32_bf16(af2[kc], wf[nt][kc], acc[h * 4 + nt], 0, 0, 0);
    }

    // epilogue: h2 store (bf16) + privatized BN sum/sumsq
    float* myslice = priv + ((blockIdx.x * 4 + wid) & (NSLICE - 1)) * 2 * DD;
    #pragma unroll
    for (int nt = 0; nt < 8; ++nt) {
        int col = nt * 16 + m;
        float bv = b2[col];
        float s = 0.f, sq = 0.f;
        #pragma unroll
        for (int r = 0; r < 4; ++r) {
            int gr = row0 + quad * 4 + r;
            if (gr < NN) {
                float v = acc[nt][r] + bv;
                C[gr * 128 + col] = f2bf(v);
                s += v;
                sq += v * v;
            }
        }
        s  += __shfl_down(s, 32, 64);  sq += __shfl_down(sq, 32, 64);
        s  += __shfl_down(s, 16, 64);  sq += __shfl_down(sq, 16, 64);
        if (quad == 0) {
            atomicAdd(&myslice[col], s);
            atomicAdd(&myslice[DD + col], sq);
        }
    }
}

// ---------------- epilogue: out = x + relu(bn(h2)), BN reduce+finalize inline ----------------

__global__ __launch_bounds__(256) void k_final(const float* __restrict__ x,
                                               const unsigned int* __restrict__ h2,
                                               float* __restrict__ out,
                                               const float* __restrict__ priv,
                                               const float* __restrict__ gamma,
                                               const float* __restrict__ beta) {
    __shared__ float ssc[DD], ssh[DD];
    int t = threadIdx.x;
    if (t < DD) {
        float s = 0.f, sq = 0.f;
        #pragma unroll
        for (int sl = 0; sl < NSLICE; ++sl) {
            s  += priv[sl * 2 * DD + t];
            sq += priv[sl * 2 * DD + DD + t];
        }
        float mean = s * (1.0f / NN);
        float var = fmaxf(sq * (1.0f / NN) - mean * mean, 0.f);
        float sc = gamma[t] * rsqrtf(var + 1e-5f);
        ssc[t] = sc;
        ssh[t] = beta[t] - mean * sc;
    }
    __syncthreads();
    #pragma unroll
    for (int u = 0; u < 4; ++u) {
        int idx = blockIdx.x * 1024 + u * 256 + t;
        if (idx >= NN * DD / 4) return;
        int c0 = (idx & 31) * 4;
        unsigned int p0 = h2[2 * idx];
        unsigned int p1 = h2[2 * idx + 1];
        float4 xv = ((const float4*)x)[idx];
        float4 o;
        o.x = xv.x + fmaxf(fmaf(bflo(p0), ssc[c0 + 0], ssh[c0 + 0]), 0.f);
        o.y = xv.y + fmaxf(fmaf(bfhi(p0), ssc[c0 + 1], ssh[c0 + 1]), 0.f);
        o.z = xv.z + fmaxf(fmaf(bflo(p1), ssc[c0 + 2], ssh[c0 + 2]), 0.f);
        o.w = xv.w + fmaxf(fmaf(bfhi(p1), ssc[c0 + 3], ssh[c0 + 3]), 0.f);
        ((float4*)out)[idx] = o;
    }
}

extern "C" void kernel_launch(void* const* d_in, const int* in_sizes, int n_in,
                              void* d_out, int out_size, void* d_ws, size_t ws_size,
                              hipStream_t stream) {
    (void)in_sizes; (void)n_in; (void)out_size; (void)ws_size;
    const float* x     = (const float*)d_in[0];
    const int*   ei    = (const int*)d_in[1];
    const float* w1    = (const float*)d_in[2];
    const float* b1    = (const float*)d_in[3];
    const float* w2    = (const float*)d_in[4];
    const float* b2    = (const float*)d_in[5];
    const float* gamma = (const float*)d_in[6];
    const float* beta  = (const float*)d_in[7];
    float* out = (float*)d_out;

    // ws layout (bytes):
    //   cursor   0x0000000  200,000     (50000 ints)   \ zeroed by ONE memset
    //   priv     0x0031000  32,768      (32x256 f32)   /  (0x39000 bytes)
    //   srcPad   0x0040000  6,400,000   (node x 64 ushort)
    //   xb       0x0680000  12,800,000  (bf16 x, packed)
    //   h0/h2    0x1300000  12,800,000  (bf16; h2 in-place over h0)
    //   wt       0x1F80000  65,536      (w1t | w2t bf16)
    // total ~33 MB
    char* wsb = (char*)d_ws;
    int*            cursor = (int*)(wsb);
    float*          priv   = (float*)(wsb + 0x31000);
    unsigned short* srcPad = (unsigned short*)(wsb + 0x40000);
    unsigned int*   xb     = (unsigned int*)(wsb + 0x680000);
    unsigned int*   h0w    = (unsigned int*)(wsb + 0x1300000);
    unsigned short* h0b    = (unsigned short*)h0w;
    unsigned short* h2b    = (unsigned short*)h0w;   // in-place (see k_mlp)
    unsigned int*   h2w    = (unsigned int*)h0w;
    unsigned short* wt     = (unsigned short*)(wsb + 0x1F80000);

    (void)hipMemsetAsync(wsb, 0, 0x39000, stream);   // cursor + priv in one shot

    k_prep<<<(32768 + NN * DD / 2 + 255) / 256, 256, 0, stream>>>(w1, w2, x, ei, cursor, srcPad, wt, xb);
    k_agg<<<(NN * 64 + 255) / 256, 256, 0, stream>>>(xb, cursor, srcPad, h0w);
    // h2 = (relu(h0@w1+b1))@w2+b2, in-place over h0, fused BN pass-1
    k_mlp<<<(NN + 63) / 64, 256, 0, stream>>>(h0b, wt, b1, b2, h2b, priv);
    k_final<<<(NN * DD / 4 + 1023) / 1024, 256, 0, stream>>>(x, h2w, out, priv, gamma, beta);
}

// Round 11
// 182.950 us; speedup vs baseline: 1.0921x; 1.0921x over previous
//
#include <hip/hip_runtime.h>
#include <hip/hip_cooperative_groups.h>

namespace cg = cooperative_groups;

#define NN 50000
#define EE 600000
#define DD 128
#define MAXDEG 64   // degrees are Poisson(12); P(deg>64) ~ 1e-28
#define NSLICE 32   // privatized BN-stat copies
#define EPT 8       // edges per scatter thread (fallback path)

typedef __attribute__((ext_vector_type(8))) short short8;
typedef __attribute__((ext_vector_type(4))) float f32x4;

static __device__ __forceinline__ unsigned short f2bf(float f) {
    unsigned int u = __float_as_uint(f);
    u += 0x7FFF + ((u >> 16) & 1);   // round-to-nearest-even
    return (unsigned short)(u >> 16);
}
static __device__ __forceinline__ float bflo(unsigned int u) {
    return __uint_as_float(u << 16);
}
static __device__ __forceinline__ float bfhi(unsigned int u) {
    return __uint_as_float(u & 0xFFFF0000u);
}

// ---- shared wave-level primitives (used by both co-op and fallback paths) ----

// 32-row GEMM: C[row0..row0+32) = act(A @ Wt + b); Wt pre-transposed [n][k];
// all fragments global->register; no LDS, no syncs.
static __device__ __forceinline__ void gemm32(const unsigned short* __restrict__ A,
                                              const unsigned short* __restrict__ W,
                                              const float* __restrict__ bias,
                                              unsigned short* __restrict__ C,
                                              float* __restrict__ priv,
                                              int lane, int row0, int relu, int unit) {
    int m = lane & 15, quad = lane >> 4;
    short8 af[2][4];
    #pragma unroll
    for (int mt = 0; mt < 2; ++mt) {
        int gr = row0 + mt * 16 + m;
        #pragma unroll
        for (int kc = 0; kc < 4; ++kc)
            af[mt][kc] = (gr < NN) ? *(const short8*)&A[gr * 128 + kc * 32 + quad * 8]
                                   : (short8)0;
    }
    f32x4 acc[2][8];
    #pragma unroll
    for (int mt = 0; mt < 2; ++mt)
        #pragma unroll
        for (int i = 0; i < 8; ++i) acc[mt][i] = (f32x4)0.f;

    #pragma unroll
    for (int h = 0; h < 2; ++h) {
        short8 wf[4][4];
        #pragma unroll
        for (int nt = 0; nt < 4; ++nt)
            #pragma unroll
            for (int kc = 0; kc < 4; ++kc)
                wf[nt][kc] = *(const short8*)&W[(h * 64 + nt * 16 + m) * 128 + kc * 32 + quad * 8];
        #pragma unroll
        for (int kc = 0; kc < 4; ++kc)
            #pragma unroll
            for (int nt = 0; nt < 4; ++nt) {
                acc[0][h * 4 + nt] = __builtin_amdgcn_mfma_f32_16x16x32_bf16(af[0][kc], wf[nt][kc], acc[0][h * 4 + nt], 0, 0, 0);
                acc[1][h * 4 + nt] = __builtin_amdgcn_mfma_f32_16x16x32_bf16(af[1][kc], wf[nt][kc], acc[1][h * 4 + nt], 0, 0, 0);
            }
    }

    if (relu) {
        #pragma unroll
        for (int nt = 0; nt < 8; ++nt) {
            int col = nt * 16 + m;
            float bv = bias[col];
            #pragma unroll
            for (int mt = 0; mt < 2; ++mt)
                #pragma unroll
                for (int r = 0; r < 4; ++r) {
                    int gr = row0 + mt * 16 + quad * 4 + r;
                    if (gr < NN) C[gr * 128 + col] = f2bf(fmaxf(acc[mt][nt][r] + bv, 0.f));
                }
        }
    } else {
        float* myslice = priv + (unit & (NSLICE - 1)) * 2 * DD;
        #pragma unroll
        for (int nt = 0; nt < 8; ++nt) {
            int col = nt * 16 + m;
            float bv = bias[col];
            float s = 0.f, sq = 0.f;
            #pragma unroll
            for (int mt = 0; mt < 2; ++mt)
                #pragma unroll
                for (int r = 0; r < 4; ++r) {
                    int gr = row0 + mt * 16 + quad * 4 + r;
                    if (gr < NN) {
                        float v = acc[mt][nt][r] + bv;
                        C[gr * 128 + col] = f2bf(v);
                        s += v;
                        sq += v * v;
                    }
                }
            s  += __shfl_down(s, 32, 64);  sq += __shfl_down(sq, 32, 64);
            s  += __shfl_down(s, 16, 64);  sq += __shfl_down(sq, 16, 64);
            if (quad == 0) {
                atomicAdd(&myslice[col], s);
                atomicAdd(&myslice[DD + col], sq);
            }
        }
    }
}

static __device__ __forceinline__ void agg_node(int node, int lane,
                                                const unsigned int* __restrict__ xb,
                                                const int* __restrict__ cursor,
                                                const unsigned short* __restrict__ srcPad,
                                                unsigned int* __restrict__ h0) {
    int cnt = cursor[node];
    if (cnt > MAXDEG) cnt = MAXDEG;
    int sv = srcPad[(node << 6) + lane];
    unsigned int self = xb[(node << 6) + lane];
    float ax = bflo(self), ay = bfhi(self);
    int j = 0;
    for (; j + 8 <= cnt; j += 8) {
        int a0 = __shfl(sv, j, 64),     a1 = __shfl(sv, j + 1, 64);
        int a2 = __shfl(sv, j + 2, 64), a3 = __shfl(sv, j + 3, 64);
        int a4 = __shfl(sv, j + 4, 64), a5 = __shfl(sv, j + 5, 64);
        int a6 = __shfl(sv, j + 6, 64), a7 = __shfl(sv, j + 7, 64);
        unsigned int u0 = xb[(a0 << 6) + lane], u1 = xb[(a1 << 6) + lane];
        unsigned int u2 = xb[(a2 << 6) + lane], u3 = xb[(a3 << 6) + lane];
        unsigned int u4 = xb[(a4 << 6) + lane], u5 = xb[(a5 << 6) + lane];
        unsigned int u6 = xb[(a6 << 6) + lane], u7 = xb[(a7 << 6) + lane];
        ax += bflo(u0) + bflo(u1) + bflo(u2) + bflo(u3)
            + bflo(u4) + bflo(u5) + bflo(u6) + bflo(u7);
        ay += bfhi(u0) + bfhi(u1) + bfhi(u2) + bfhi(u3)
            + bfhi(u4) + bfhi(u5) + bfhi(u6) + bfhi(u7);
    }
    for (; j + 4 <= cnt; j += 4) {
        int a0 = __shfl(sv, j, 64),     a1 = __shfl(sv, j + 1, 64);
        int a2 = __shfl(sv, j + 2, 64), a3 = __shfl(sv, j + 3, 64);
        unsigned int u0 = xb[(a0 << 6) + lane], u1 = xb[(a1 << 6) + lane];
        unsigned int u2 = xb[(a2 << 6) + lane], u3 = xb[(a3 << 6) + lane];
        ax += bflo(u0) + bflo(u1) + bflo(u2) + bflo(u3);
        ay += bfhi(u0) + bfhi(u1) + bfhi(u2) + bfhi(u3);
    }
    for (; j < cnt; ++j) {
        int s = __shfl(sv, j, 64);
        unsigned int u = xb[(s << 6) + lane];
        ax += bflo(u);
        ay += bfhi(u);
    }
    h0[(node << 6) + lane] = (unsigned int)f2bf(ax) | ((unsigned int)f2bf(ay) << 16);
}

// ---------------- cooperative megakernel (grid-stride phases, any grid size) ----------------

__global__ __launch_bounds__(256) void k_all(const float* __restrict__ x,
                                             const int* __restrict__ ei,
                                             const float* __restrict__ w1,
                                             const float* __restrict__ b1,
                                             const float* __restrict__ w2,
                                             const float* __restrict__ b2,
                                             const float* __restrict__ gamma,
                                             const float* __restrict__ beta,
                                             float* __restrict__ out,
                                             char* __restrict__ wsb) {
    cg::grid_group grid = cg::this_grid();
    int*            cursor = (int*)wsb;
    float*          priv   = (float*)(wsb + 0x31000);
    unsigned short* srcPad = (unsigned short*)(wsb + 0x40000);
    unsigned int*   xb     = (unsigned int*)(wsb + 0x680000);
    unsigned int*   h0w    = (unsigned int*)(wsb + 0x1300000);
    unsigned short* h1b    = (unsigned short*)(wsb + 0x1F80000);
    unsigned int*   h2w    = (unsigned int*)(wsb + 0x2C00000);
    unsigned short* wt     = (unsigned short*)(wsb + 0x3880000);
    const unsigned short* h0b = (const unsigned short*)h0w;
    unsigned short*       h2b = (unsigned short*)h2w;

    int nth = gridDim.x * 256;
    int nwave = nth >> 6;
    int tid = blockIdx.x * 256 + threadIdx.x;
    int lane = tid & 63;
    int gwave = tid >> 6;

    // phase 0: zero cursor + priv
    for (int i = tid; i < NN; i += nth) cursor[i] = 0;
    for (int i = tid; i < NSLICE * 2 * DD; i += nth) priv[i] = 0.f;
    grid.sync();

    // phase 1: adjacency scatter + weight transpose + x->bf16
    for (int e = tid; e < EE; e += nth) {
        int s = ei[e];
        int d = ei[EE + e];
        int pos = atomicAdd(&cursor[d], 1);
        if (pos < MAXDEG) srcPad[(d << 6) + pos] = (unsigned short)s;
    }
    for (int i = tid; i < 32768; i += nth) {
        int w = i >> 14, idx = i & 16383;
        int k = idx >> 7, n = idx & 127;
        const float* src = w ? w2 : w1;
        wt[w * 16384 + n * 128 + k] = f2bf(src[k * 128 + n]);
    }
    for (int xi = tid; xi < NN * DD / 2; xi += nth) {
        float2 v = ((const float2*)x)[xi];
        xb[xi] = (unsigned int)f2bf(v.x) | ((unsigned int)f2bf(v.y) << 16);
    }
    grid.sync();

    // phase 2: aggregation (wave per node)
    for (int node = gwave; node < NN; node += nwave)
        agg_node(node, lane, xb, cursor, srcPad, h0w);
    grid.sync();

    // phase 3: h1 = relu(h0 @ W1 + b1)
    for (int unit = gwave; unit * 32 < NN; unit += nwave)
        gemm32(h0b, wt, b1, h1b, nullptr, lane, unit * 32, 1, unit);
    grid.sync();

    // phase 4: h2 = h1 @ W2 + b2, fused privatized BN pass-1
    for (int unit = gwave; unit * 32 < NN; unit += nwave)
        gemm32(h1b, wt + 16384, b2, h2b, priv, lane, unit * 32, 0, unit);
    grid.sync();

    // phase 5: BN finalize (per block) + out = x + relu(bn(h2))
    __shared__ float ssc[DD], ssh[DD];
    int t = threadIdx.x;
    if (t < DD) {
        float s = 0.f, sq = 0.f;
        #pragma unroll
        for (int sl = 0; sl < NSLICE; ++sl) {
            s  += priv[sl * 2 * DD + t];
            sq += priv[sl * 2 * DD + DD + t];
        }
        float mean = s * (1.0f / NN);
        float var = fmaxf(sq * (1.0f / NN) - mean * mean, 0.f);
        float sc = gamma[t] * rsqrtf(var + 1e-5f);
        ssc[t] = sc;
        ssh[t] = beta[t] - mean * sc;
    }
    __syncthreads();
    for (int idx = tid; idx < NN * DD / 4; idx += nth) {
        int c0 = (idx & 31) * 4;
        unsigned int p0 = h2w[2 * idx];
        unsigned int p1 = h2w[2 * idx + 1];
        float4 xv = ((const float4*)x)[idx];
        float4 o;
        o.x = xv.x + fmaxf(fmaf(bflo(p0), ssc[c0 + 0], ssh[c0 + 0]), 0.f);
        o.y = xv.y + fmaxf(fmaf(bfhi(p0), ssc[c0 + 1], ssh[c0 + 1]), 0.f);
        o.z = xv.z + fmaxf(fmaf(bflo(p1), ssc[c0 + 2], ssh[c0 + 2]), 0.f);
        o.w = xv.w + fmaxf(fmaf(bfhi(p1), ssc[c0 + 3], ssh[c0 + 3]), 0.f);
        ((float4*)out)[idx] = o;
    }
}

// ---------------- fallback path: R8's proven kernels ----------------

__global__ __launch_bounds__(256) void k_prep(const float* __restrict__ w1,
                                              const float* __restrict__ w2,
                                              const float* __restrict__ x,
                                              const int* __restrict__ ei,
                                              int* __restrict__ cursor,
                                              unsigned short* __restrict__ srcPad,
                                              unsigned short* __restrict__ wt,
                                              unsigned int* __restrict__ xb) {
    int tid = blockIdx.x * 256 + threadIdx.x;
    if (tid < EE / EPT) {
        #pragma unroll
        for (int i = 0; i < EPT; ++i) {
            int e = tid + i * (EE / EPT);
            int s = ei[e];
            int d = ei[EE + e];
            int pos = atomicAdd(&cursor[d], 1);
            if (pos < MAXDEG) srcPad[(d << 6) + pos] = (unsigned short)s;
        }
    }
    if (tid < 32768) {
        int w = tid >> 14, idx = tid & 16383;
        int k = idx >> 7, n = idx & 127;
        const float* src = w ? w2 : w1;
        wt[w * 16384 + n * 128 + k] = f2bf(src[k * 128 + n]);
    }
    int xi = tid - 32768;
    if (xi >= 0 && xi < NN * DD / 2) {
        float2 v = ((const float2*)x)[xi];
        xb[xi] = (unsigned int)f2bf(v.x) | ((unsigned int)f2bf(v.y) << 16);
    }
}

__global__ __launch_bounds__(256) void k_agg(const unsigned int* __restrict__ xb,
                                             const int* __restrict__ cursor,
                                             const unsigned short* __restrict__ srcPad,
                                             unsigned int* __restrict__ h0) {
    int wave = (blockIdx.x * blockDim.x + threadIdx.x) >> 6;
    int lane = threadIdx.x & 63;
    if (wave >= NN) return;
    agg_node(wave, lane, xb, cursor, srcPad, h0);
}

__global__ __launch_bounds__(256) void k_gemm(const unsigned short* __restrict__ A,
                                              const unsigned short* __restrict__ W,
                                              const float* __restrict__ bias,
                                              unsigned short* __restrict__ Cb,
                                              float* __restrict__ priv,
                                              int relu) {
    int wave = (blockIdx.x * 256 + threadIdx.x) >> 6;
    int lane = threadIdx.x & 63;
    int row0 = wave * 32;
    if (row0 >= NN) return;
    gemm32(A, W, bias, Cb, priv, lane, row0, relu, wave);
}

__global__ __launch_bounds__(256) void k_final(const float* __restrict__ x,
                                               const unsigned int* __restrict__ h2,
                                               float* __restrict__ out,
                                               const float* __restrict__ priv,
                                               const float* __restrict__ gamma,
                                               const float* __restrict__ beta) {
    __shared__ float ssc[DD], ssh[DD];
    int t = threadIdx.x;
    if (t < DD) {
        float s = 0.f, sq = 0.f;
        #pragma unroll
        for (int sl = 0; sl < NSLICE; ++sl) {
            s  += priv[sl * 2 * DD + t];
            sq += priv[sl * 2 * DD + DD + t];
        }
        float mean = s * (1.0f / NN);
        float var = fmaxf(sq * (1.0f / NN) - mean * mean, 0.f);
        float sc = gamma[t] * rsqrtf(var + 1e-5f);
        ssc[t] = sc;
        ssh[t] = beta[t] - mean * sc;
    }
    __syncthreads();
    #pragma unroll
    for (int u = 0; u < 4; ++u) {
        int idx = blockIdx.x * 1024 + u * 256 + t;
        if (idx >= NN * DD / 4) return;
        int c0 = (idx & 31) * 4;
        unsigned int p0 = h2[2 * idx];
        unsigned int p1 = h2[2 * idx + 1];
        float4 xv = ((const float4*)x)[idx];
        float4 o;
        o.x = xv.x + fmaxf(fmaf(bflo(p0), ssc[c0 + 0], ssh[c0 + 0]), 0.f);
        o.y = xv.y + fmaxf(fmaf(bfhi(p0), ssc[c0 + 1], ssh[c0 + 1]), 0.f);
        o.z = xv.z + fmaxf(fmaf(bflo(p1), ssc[c0 + 2], ssh[c0 + 2]), 0.f);
        o.w = xv.w + fmaxf(fmaf(bfhi(p1), ssc[c0 + 3], ssh[c0 + 3]), 0.f);
        ((float4*)out)[idx] = o;
    }
}

extern "C" void kernel_launch(void* const* d_in, const int* in_sizes, int n_in,
                              void* d_out, int out_size, void* d_ws, size_t ws_size,
                              hipStream_t stream) {
    (void)in_sizes; (void)n_in; (void)out_size; (void)ws_size;
    const float* x     = (const float*)d_in[0];
    const int*   ei    = (const int*)d_in[1];
    const float* w1    = (const float*)d_in[2];
    const float* b1    = (const float*)d_in[3];
    const float* w2    = (const float*)d_in[4];
    const float* b2    = (const float*)d_in[5];
    const float* gamma = (const float*)d_in[6];
    const float* beta  = (const float*)d_in[7];
    float* out = (float*)d_out;
    char* wsb  = (char*)d_ws;

    // ws layout (bytes): cursor 0x0 (200000) | priv 0x31000 (32768) |
    // srcPad 0x40000 (6.4MB) | xb 0x680000 (12.8MB) | h0 0x1300000 (12.8MB) |
    // h1 0x1F80000 (12.8MB) | h2 0x2C00000 (12.8MB) | wt 0x3880000 (64KB)
    int*            cursor = (int*)wsb;
    float*          priv   = (float*)(wsb + 0x31000);
    unsigned short* srcPad = (unsigned short*)(wsb + 0x40000);
    unsigned int*   xb     = (unsigned int*)(wsb + 0x680000);
    unsigned int*   h0w    = (unsigned int*)(wsb + 0x1300000);
    unsigned short* h1b    = (unsigned short*)(wsb + 0x1F80000);
    unsigned int*   h2w    = (unsigned int*)(wsb + 0x2C00000);
    unsigned short* wt     = (unsigned short*)(wsb + 0x3880000);
    const unsigned short* h0b = (const unsigned short*)h0w;
    unsigned short*       h2b = (unsigned short*)h2w;

    // ---- try cooperative single-dispatch path (guarded, capture-safe queries) ----
    bool coop_ok = false;
    int dev = 0;
    if (hipGetDevice(&dev) == hipSuccess) {
        int has_coop = 0;
        if (hipDeviceGetAttribute(&has_coop, hipDeviceAttributeCooperativeLaunch, dev) == hipSuccess
            && has_coop) {
            int blocks_per_cu = 0;
            if (hipOccupancyMaxActiveBlocksPerMultiprocessor(
                    &blocks_per_cu, reinterpret_cast<const void*>(&k_all), 256, 0) == hipSuccess
                && blocks_per_cu > 0) {
                int nb = blocks_per_cu * 256;          // 256 CUs
                if (nb > 2048) nb = 2048;
                void* args[] = {(void*)&x, (void*)&ei, (void*)&w1, (void*)&b1, (void*)&w2,
                                (void*)&b2, (void*)&gamma, (void*)&beta, (void*)&out, (void*)&wsb};
                if (hipLaunchCooperativeKernel(reinterpret_cast<const void*>(&k_all),
                                               dim3(nb), dim3(256), args, 0, stream) == hipSuccess)
                    coop_ok = true;
            }
        }
    }
    if (coop_ok) return;

    // ---- fallback: R8's proven multi-dispatch path ----
    (void)hipMemsetAsync(wsb, 0, 0x39000, stream);   // cursor + priv
    k_prep<<<(32768 + NN * DD / 2 + 255) / 256, 256, 0, stream>>>(w1, w2, x, ei, cursor, srcPad, wt, xb);
    k_agg<<<(NN * 64 + 255) / 256, 256, 0, stream>>>(xb, cursor, srcPad, h0w);
    k_gemm<<<(NN + 127) / 128, 256, 0, stream>>>(h0b, wt, b1, h1b, nullptr, 1);
    k_gemm<<<(NN + 127) / 128, 256, 0, stream>>>(h1b, wt + 16384, b2, h2b, priv, 0);
    k_final<<<(NN * DD / 4 + 1023) / 1024, 256, 0, stream>>>(x, h2w, out, priv, gamma, beta);
}